// Round 3
// baseline (367.165 us; speedup 1.0000x reference)
//
#include <hip/hip_runtime.h>

#define HOG_PI  3.14159265358979323846f
#define HOG_PI2 1.57079632679489661923f

// Four workgroups per image. Band q covers pixel rows 64q .. 64q+79 (last band
// 64 rows), i.e. cell rows 4q..4q+4 and block rows 4q..4q+3 (last band 3).
// Thread map: xq=t&31 (float4 column), yg=t>>5; rows stride 8.
// grid = 4*B = 2048 -> 8 blocks/CU, launch_bounds(256,8) -> 32 waves/CU.
__global__ __launch_bounds__(256, 8) void hog_kernel(
    const float* __restrict__ img, const int* __restrict__ targets,
    const int* __restrict__ camid, float* __restrict__ out, int B) {
  const int bb = blockIdx.x;
  const int b = bb >> 2;
  const int band = bb & 3;
  const int t = threadIdx.x;
  const float* im = img + (size_t)b * (3 * 256 * 128);

  __shared__ float part[256][9];   // thread-private partial histograms
  __shared__ float cellh[5][8][9]; // cell rows local to this band

#pragma unroll
  for (int k = 0; k < 9; ++k) part[t][k] = 0.0f;
  for (int i = t; i < 5 * 8 * 9; i += 256) ((float*)cellh)[i] = 0.0f;
  __syncthreads();

  const int xq = t & 31;   // float4 column 0..31
  const int yg = t >> 5;   // 0..7
  const int x0 = xq * 4;
  const int cx = xq >> 2;  // cell column 0..7
  const int rbase = band * 64;
  const int nj = (band == 3) ? 8 : 10;

  for (int j = 0; j < nj; ++j) {
    const int y = rbase + yg + 8 * j;
    const int ym = (y == 0) ? 0 : y - 1;
    const int yp = (y == 255) ? 255 : y + 1;
    float dxv[3][4], dyv[3][4];
#pragma unroll
    for (int c = 0; c < 3; ++c) {
      const float* rc = im + c * 32768 + y * 128;
      const float* ru = im + c * 32768 + ym * 128;
      const float* rd = im + c * 32768 + yp * 128;
      const float4 cc = *(const float4*)(rc + x0);
      const float4 uu = *(const float4*)(ru + x0);
      const float4 dd = *(const float4*)(rd + x0);
      const float lf = (x0 == 0) ? cc.x : rc[x0 - 1];
      const float rf = (x0 == 124) ? cc.w : rc[x0 + 4];
      dxv[c][0] = cc.y - lf;
      dxv[c][1] = cc.z - cc.x;
      dxv[c][2] = cc.w - cc.y;
      dxv[c][3] = rf - cc.z;
      dyv[c][0] = dd.x - uu.x;
      dyv[c][1] = dd.y - uu.y;
      dyv[c][2] = dd.z - uu.z;
      dyv[c][3] = dd.w - uu.w;
    }
#pragma unroll
    for (int i = 0; i < 4; ++i) {
      // channel argmax, first-max wins on ties (strict >)
      float dxs = dxv[0][i], dys = dyv[0][i];
      float g = dxs * dxs + dys * dys;
      const float g1 = dxv[1][i] * dxv[1][i] + dyv[1][i] * dyv[1][i];
      if (g1 > g) { dxs = dxv[1][i]; dys = dyv[1][i]; g = g1; }
      const float g2 = dxv[2][i] * dxv[2][i] + dyv[2][i] * dyv[2][i];
      if (g2 > g) { dxs = dxv[2][i]; dys = dyv[2][i]; g = g2; }
      const float mag = __builtin_amdgcn_sqrtf(g);
      // unsigned angle mod pi: flip so dy >= 0 (same angle mod pi)
      if (dys < 0.0f) { dys = -dys; dxs = -dxs; }
      const float ax = fabsf(dxs);
      const float mn = fminf(ax, dys), mx = fmaxf(ax, dys);
      const float a = mn * __builtin_amdgcn_rcpf(fmaxf(mx, 1e-30f));
      const float s = a * a;
      // atan(a), a in [0,1]; max err ~1e-5 rad
      float th = ((((0.0208351f * s - 0.0851330f) * s + 0.1801410f) * s
                   - 0.3302995f) * s + 0.9998660f) * a;
      if (dys > ax) th = HOG_PI2 - th;   // atan(dy/|dx|) in [0, pi/2]
      if (dxs < 0.0f) th = HOG_PI - th;  // reflect -> [0, pi]
      const float pos = th * (9.0f / HOG_PI) - 0.5f;  // in [-0.5, 8.5]
      const float bf = floorf(pos);
      const float frac = pos - bf;
      const int b0 = (int)bf;  // in [-1, 8]
      const int b0i = (b0 < 0) ? 8 : b0;
      const int b1i = (b0i == 8) ? 0 : b0i + 1;
      atomicAdd(&part[t][b0i], mag * (1.0f - frac));
      atomicAdd(&part[t][b1i], mag * frac);
    }
    if (j & 1) {  // finished a 16-row cell band: flush private row -> cell hist
      const int m = j >> 1;
#pragma unroll
      for (int k = 0; k < 9; ++k) {
        atomicAdd(&cellh[m][cx][k], part[t][k]);
        part[t][k] = 0.0f;
      }
    }
  }
  __syncthreads();

  float* outF = out + (size_t)b * 4096;
  const int nby = (band == 3) ? 3 : 4;
  if (t < nby * 7) {
    const int byl = t / 7;
    const int bx = t - byl * 7;
    const int byg = band * 4 + byl;
    float v[36];
#pragma unroll
    for (int q = 0; q < 4; ++q) {
      const int cy = byl + (q >> 1);
      const int cc = bx + (q & 1);
#pragma unroll
      for (int k = 0; k < 9; ++k) v[q * 9 + k] = cellh[cy][cc][k];
    }
    float ss = 0.0f;
#pragma unroll
    for (int jj = 0; jj < 36; ++jj) ss += v[jj] * v[jj];
    const float s1 = 1.0f / (sqrtf(ss) + 3.6f);  // sz*0.1 = 36*0.1
    float ss2 = 0.0f;
#pragma unroll
    for (int jj = 0; jj < 36; ++jj) {
      v[jj] = fminf(v[jj] * s1, 0.2f);
      ss2 += v[jj] * v[jj];
    }
    const float s2 = 1.0f / (sqrtf(ss2) + 1e-3f);
    float4* dst = (float4*)(outF + (byg * 7 + bx) * 36);
#pragma unroll
    for (int q = 0; q < 9; ++q)
      dst[q] = make_float4(v[4 * q] * s2, v[4 * q + 1] * s2,
                           v[4 * q + 2] * s2, v[4 * q + 3] * s2);
  }
  if (band == 3) {
    // zero the pad region [3780, 4096) and write passthrough outputs
    for (int i = 3780 + t; i < 4096; i += 256) outF[i] = 0.0f;
    if (t == 64) out[(size_t)B * 4096 + b] = (float)targets[b];
    if (t == 65) out[(size_t)B * 4096 + B + b] = (float)camid[b];
  }
}

extern "C" void kernel_launch(void* const* d_in, const int* in_sizes, int n_in,
                              void* d_out, int out_size, void* d_ws, size_t ws_size,
                              hipStream_t stream) {
  const float* images = (const float*)d_in[0];
  const int* targets = (const int*)d_in[1];
  const int* camid = (const int*)d_in[2];
  float* out = (float*)d_out;
  const int B = in_sizes[1];  // 512
  hipLaunchKernelGGL(hog_kernel, dim3(B * 4), dim3(256), 0, stream,
                     images, targets, camid, out, B);
}

// Round 4
// 336.048 us; speedup vs baseline: 1.0926x; 1.0926x over previous
//
#include <hip/hip_runtime.h>

#define HOG_PI  3.14159265358979323846f
#define HOG_PI2 1.57079632679489661923f

// Two workgroups per image: half 0 -> rows 0..143 (cell bands 0..8),
// half 1 -> rows 128..255 (cell bands 8..15). Thread map: xq=t&31 (float4
// column), yg=t>>5; rows stride 8. Explicit next-iteration prefetch (9 float4
// in flight) + shfl halo; NO launch_bounds (R2/R3 regression = VGPR cap
// serializing loads).
__global__ void hog_kernel(
    const float* __restrict__ img, const int* __restrict__ targets,
    const int* __restrict__ camid, float* __restrict__ out, int B) {
  const int bb = blockIdx.x;
  const int b = bb >> 1;
  const int half = bb & 1;
  const int t = threadIdx.x;
  const float* im = img + (size_t)b * (3 * 256 * 128);

  __shared__ float part[256][9];    // thread-private partial histograms
  __shared__ float cellh[9][8][9];  // local cell bands, 8 cols, 9 bins

#pragma unroll
  for (int k = 0; k < 9; ++k) part[t][k] = 0.0f;
  for (int i = t; i < 9 * 8 * 9; i += 256) ((float*)cellh)[i] = 0.0f;
  __syncthreads();

  const int xq = t & 31;   // float4 column 0..31
  const int yg = t >> 5;   // 0..7
  const int x0 = xq * 4;
  const int cx = xq >> 2;  // cell column 0..7
  const int lane = t & 63;
  const int lm = (xq == 0) ? lane : lane - 1;   // shfl source for left halo
  const int lp = (xq == 31) ? lane : lane + 1;  // shfl source for right halo
  const int rbase = half ? 128 : 0;
  const int nj = half ? 16 : 18;

  float4 cc0, cc1, cc2, uu0, uu1, uu2, dd0, dd1, dd2;
  {
    const int y = rbase + yg;
    const int ym = (y == 0) ? 0 : y - 1;
    const int yp = y + 1;
    const float* p0 = im + y * 128 + x0;
    const float* u0 = im + ym * 128 + x0;
    const float* d0 = im + yp * 128 + x0;
    cc0 = *(const float4*)(p0);          uu0 = *(const float4*)(u0);          dd0 = *(const float4*)(d0);
    cc1 = *(const float4*)(p0 + 32768);  uu1 = *(const float4*)(u0 + 32768);  dd1 = *(const float4*)(d0 + 32768);
    cc2 = *(const float4*)(p0 + 65536);  uu2 = *(const float4*)(u0 + 65536);  dd2 = *(const float4*)(d0 + 65536);
  }

  for (int j = 0; j < nj; ++j) {
    float4 nc0, nc1, nc2, nu0, nu1, nu2, nd0, nd1, nd2;
    if (j + 1 < nj) {  // prefetch next iteration's rows (address-independent)
      const int y = rbase + yg + 8 * (j + 1);
      const int yp = (y == 255) ? 255 : y + 1;
      const float* p0 = im + y * 128 + x0;
      const float* u0 = im + (y - 1) * 128 + x0;
      const float* d0 = im + yp * 128 + x0;
      nc0 = *(const float4*)(p0);          nu0 = *(const float4*)(u0);          nd0 = *(const float4*)(d0);
      nc1 = *(const float4*)(p0 + 32768);  nu1 = *(const float4*)(u0 + 32768);  nd1 = *(const float4*)(d0 + 32768);
      nc2 = *(const float4*)(p0 + 65536);  nu2 = *(const float4*)(u0 + 65536);  nd2 = *(const float4*)(d0 + 65536);
    }

    float dxv[3][4], dyv[3][4];
#pragma unroll
    for (int c = 0; c < 3; ++c) {
      const float4 cc = (c == 0) ? cc0 : (c == 1) ? cc1 : cc2;
      const float4 uu = (c == 0) ? uu0 : (c == 1) ? uu1 : uu2;
      const float4 dd = (c == 0) ? dd0 : (c == 1) ? dd1 : dd2;
      float lf = __shfl(cc.w, lm, 64);
      float rf = __shfl(cc.x, lp, 64);
      if (xq == 0) lf = cc.x;
      if (xq == 31) rf = cc.w;
      dxv[c][0] = cc.y - lf;
      dxv[c][1] = cc.z - cc.x;
      dxv[c][2] = cc.w - cc.y;
      dxv[c][3] = rf - cc.z;
      dyv[c][0] = dd.x - uu.x;
      dyv[c][1] = dd.y - uu.y;
      dyv[c][2] = dd.z - uu.z;
      dyv[c][3] = dd.w - uu.w;
    }
#pragma unroll
    for (int i = 0; i < 4; ++i) {
      // channel argmax, first-max wins on ties (strict >)
      float dxs = dxv[0][i], dys = dyv[0][i];
      float g = dxs * dxs + dys * dys;
      const float g1 = dxv[1][i] * dxv[1][i] + dyv[1][i] * dyv[1][i];
      if (g1 > g) { dxs = dxv[1][i]; dys = dyv[1][i]; g = g1; }
      const float g2 = dxv[2][i] * dxv[2][i] + dyv[2][i] * dyv[2][i];
      if (g2 > g) { dxs = dxv[2][i]; dys = dyv[2][i]; g = g2; }
      const float mag = sqrtf(g);
      // unsigned angle mod pi: flip so dy >= 0 (same angle mod pi)
      if (dys < 0.0f) { dys = -dys; dxs = -dxs; }
      const float ax = fabsf(dxs);
      const float mn = fminf(ax, dys), mx = fmaxf(ax, dys);
      const float a = mn * __builtin_amdgcn_rcpf(fmaxf(mx, 1e-30f));
      const float s = a * a;
      float th = ((((0.0208351f * s - 0.0851330f) * s + 0.1801410f) * s
                   - 0.3302995f) * s + 0.9998660f) * a;
      if (dys > ax) th = HOG_PI2 - th;
      if (dxs < 0.0f) th = HOG_PI - th;
      const float pos = th * (9.0f / HOG_PI) - 0.5f;  // [-0.5, 8.5]
      const float bf = floorf(pos);
      const float frac = pos - bf;
      const int b0 = (int)bf;  // [-1, 8]
      const int b0i = (b0 < 0) ? 8 : b0;
      const int b1i = (b0i == 8) ? 0 : b0i + 1;
      atomicAdd(&part[t][b0i], mag * (1.0f - frac));
      atomicAdd(&part[t][b1i], mag * frac);
    }
    if (j & 1) {  // finished a 16-row cell band: flush private row -> cell hist
      const int m = j >> 1;
#pragma unroll
      for (int k = 0; k < 9; ++k) {
        atomicAdd(&cellh[m][cx][k], part[t][k]);
        part[t][k] = 0.0f;
      }
    }
    cc0 = nc0; cc1 = nc1; cc2 = nc2;
    uu0 = nu0; uu1 = nu1; uu2 = nu2;
    dd0 = nd0; dd1 = nd1; dd2 = nd2;
  }
  __syncthreads();

  float* outF = out + (size_t)b * 4096;
  const int nby = half ? 7 : 8;
  if (t < nby * 7) {
    const int byl = t / 7;
    const int bx = t - byl * 7;
    const int byg = half ? (8 + byl) : byl;
    float v[36];
#pragma unroll
    for (int q = 0; q < 4; ++q) {
      const int cy = byl + (q >> 1);
      const int ccx = bx + (q & 1);
#pragma unroll
      for (int k = 0; k < 9; ++k) v[q * 9 + k] = cellh[cy][ccx][k];
    }
    float ss = 0.0f;
#pragma unroll
    for (int jj = 0; jj < 36; ++jj) ss += v[jj] * v[jj];
    const float s1 = 1.0f / (sqrtf(ss) + 3.6f);  // sz*0.1 = 36*0.1
    float ss2 = 0.0f;
#pragma unroll
    for (int jj = 0; jj < 36; ++jj) {
      v[jj] = fminf(v[jj] * s1, 0.2f);
      ss2 += v[jj] * v[jj];
    }
    const float s2 = 1.0f / (sqrtf(ss2) + 1e-3f);
    float4* dst = (float4*)(outF + (byg * 7 + bx) * 36);
#pragma unroll
    for (int q = 0; q < 9; ++q)
      dst[q] = make_float4(v[4 * q] * s2, v[4 * q + 1] * s2,
                           v[4 * q + 2] * s2, v[4 * q + 3] * s2);
  }
  if (half) {
    for (int i = 3780 + t; i < 4096; i += 256) outF[i] = 0.0f;
    if (t == 64) out[(size_t)B * 4096 + b] = (float)targets[b];
    if (t == 65) out[(size_t)B * 4096 + B + b] = (float)camid[b];
  }
}

extern "C" void kernel_launch(void* const* d_in, const int* in_sizes, int n_in,
                              void* d_out, int out_size, void* d_ws, size_t ws_size,
                              hipStream_t stream) {
  const float* images = (const float*)d_in[0];
  const int* targets = (const int*)d_in[1];
  const int* camid = (const int*)d_in[2];
  float* out = (float*)d_out;
  const int B = in_sizes[1];  // 512
  hipLaunchKernelGGL(hog_kernel, dim3(B * 2), dim3(256), 0, stream,
                     images, targets, camid, out, B);
}

// Round 5
// 71.805 us; speedup vs baseline: 5.1134x; 4.6800x over previous
//
#include <hip/hip_runtime.h>

#define HOG_PI  3.14159265358979323846f
#define HOG_PI2 1.57079632679489661923f

// One block per image, 256 threads = 32 float4-cols (xq) x 8 slots (s).
// Slot s handles cell bands s and s+8 (16 rows each) sequentially.
// Per-thread 9-bin histogram lives in REGISTERS (unrolled compare-select);
// band flush = 4-lane shfl reduce + single non-atomic ds_write per bin.
// NO LDS atomics anywhere (R1-R4 fit: runtime ~ lane-atomic count).
__global__ void hog_kernel(const float* __restrict__ img,
                           const int* __restrict__ targets,
                           const int* __restrict__ camid,
                           float* __restrict__ out, int B) {
  const int b = blockIdx.x;
  const int t = threadIdx.x;
  const float* im = img + (size_t)b * (3 * 256 * 128);

  __shared__ float cellh[16][8][9];  // 4.6 KB; each entry written exactly once

  const int xq = t & 31;   // float4 column 0..31
  const int s = t >> 5;    // slot 0..7
  const int x0 = xq * 4;
  const int cx = xq >> 2;  // cell column 0..7
  const int lane = t & 63;
  const int lm = (xq == 0) ? lane : lane - 1;   // left-halo shfl source
  const int lp = (xq == 31) ? lane : lane + 1;  // right-halo shfl source

#pragma unroll
  for (int pass = 0; pass < 2; ++pass) {
    const int m = s + pass * 8;  // cell band 0..15
    const int r0 = m * 16;
    float h[9];
#pragma unroll
    for (int k = 0; k < 9; ++k) h[k] = 0.0f;

    const float* ch0 = im;
    const float* ch1 = im + 32768;
    const float* ch2 = im + 65536;
    const int rp = (r0 == 0) ? 0 : r0 - 1;
    // rolling window: p=row y-1, c=row y, n=row y+1 (3 channels)
    float4 p0 = *(const float4*)(ch0 + rp * 128 + x0);
    float4 p1 = *(const float4*)(ch1 + rp * 128 + x0);
    float4 p2 = *(const float4*)(ch2 + rp * 128 + x0);
    float4 c0 = *(const float4*)(ch0 + r0 * 128 + x0);
    float4 c1 = *(const float4*)(ch1 + r0 * 128 + x0);
    float4 c2 = *(const float4*)(ch2 + r0 * 128 + x0);

    for (int r = 0; r < 16; ++r) {
      const int y = r0 + r;
      const int yn = (y == 255) ? 255 : y + 1;
      const float4 n0 = *(const float4*)(ch0 + yn * 128 + x0);
      const float4 n1 = *(const float4*)(ch1 + yn * 128 + x0);
      const float4 n2 = *(const float4*)(ch2 + yn * 128 + x0);

      float dxv[3][4], dyv[3][4];
#pragma unroll
      for (int c = 0; c < 3; ++c) {
        const float4 cc = (c == 0) ? c0 : (c == 1) ? c1 : c2;
        const float4 pp = (c == 0) ? p0 : (c == 1) ? p1 : p2;
        const float4 nn = (c == 0) ? n0 : (c == 1) ? n1 : n2;
        float lf = __shfl(cc.w, lm, 64);
        float rf = __shfl(cc.x, lp, 64);
        if (xq == 0) lf = cc.x;
        if (xq == 31) rf = cc.w;
        dxv[c][0] = cc.y - lf;
        dxv[c][1] = cc.z - cc.x;
        dxv[c][2] = cc.w - cc.y;
        dxv[c][3] = rf - cc.z;
        dyv[c][0] = nn.x - pp.x;
        dyv[c][1] = nn.y - pp.y;
        dyv[c][2] = nn.z - pp.z;
        dyv[c][3] = nn.w - pp.w;
      }
#pragma unroll
      for (int i = 0; i < 4; ++i) {
        // channel argmax, first-max wins on ties (strict >)
        float dxs = dxv[0][i], dys = dyv[0][i];
        float g = dxs * dxs + dys * dys;
        const float g1 = dxv[1][i] * dxv[1][i] + dyv[1][i] * dyv[1][i];
        if (g1 > g) { dxs = dxv[1][i]; dys = dyv[1][i]; g = g1; }
        const float g2 = dxv[2][i] * dxv[2][i] + dyv[2][i] * dyv[2][i];
        if (g2 > g) { dxs = dxv[2][i]; dys = dyv[2][i]; g = g2; }
        const float mag = sqrtf(g);
        // unsigned angle mod pi: flip so dy >= 0
        if (dys < 0.0f) { dys = -dys; dxs = -dxs; }
        const float ax = fabsf(dxs);
        const float mn = fminf(ax, dys), mx = fmaxf(ax, dys);
        const float a = mn * __builtin_amdgcn_rcpf(fmaxf(mx, 1e-30f));
        const float sq = a * a;
        float th = ((((0.0208351f * sq - 0.0851330f) * sq + 0.1801410f) * sq
                     - 0.3302995f) * sq + 0.9998660f) * a;
        if (dys > ax) th = HOG_PI2 - th;
        if (dxs < 0.0f) th = HOG_PI - th;
        const float pos = th * (9.0f / HOG_PI) - 0.5f;  // [-0.5, 8.5]
        const float bf = floorf(pos);
        const float frac = pos - bf;
        const int b0 = (int)bf;  // [-1, 8]
        const int b0i = (b0 < 0) ? 8 : b0;
        const int b1i = (b0i == 8) ? 0 : b0i + 1;
        const float w0 = mag * (1.0f - frac);
        const float w1 = mag * frac;
        // register histogram: static indices, predicated adds, no DS ops
#pragma unroll
        for (int k = 0; k < 9; ++k)
          h[k] += ((b0i == k) ? w0 : 0.0f) + ((b1i == k) ? w1 : 0.0f);
      }
      p0 = c0; p1 = c1; p2 = c2;
      c0 = n0; c1 = n1; c2 = n2;
    }
    // flush band: reduce across the 4 lanes sharing this cell column
#pragma unroll
    for (int k = 0; k < 9; ++k) {
      float v = h[k];
      v += __shfl_xor(v, 1, 64);
      v += __shfl_xor(v, 2, 64);
      if ((xq & 3) == 0) cellh[m][cx][k] = v;  // each entry written once
    }
  }
  __syncthreads();

  float* outF = out + (size_t)b * 4096;
  if (t < 105) {
    const int by = t / 7;
    const int bx = t - by * 7;
    float v[36];
#pragma unroll
    for (int q = 0; q < 4; ++q) {
      const int cy = by + (q >> 1);
      const int ccx = bx + (q & 1);
#pragma unroll
      for (int k = 0; k < 9; ++k) v[q * 9 + k] = cellh[cy][ccx][k];
    }
    float ss = 0.0f;
#pragma unroll
    for (int jj = 0; jj < 36; ++jj) ss += v[jj] * v[jj];
    const float s1 = 1.0f / (sqrtf(ss) + 3.6f);  // sz*0.1 = 36*0.1
    float ss2 = 0.0f;
#pragma unroll
    for (int jj = 0; jj < 36; ++jj) {
      v[jj] = fminf(v[jj] * s1, 0.2f);
      ss2 += v[jj] * v[jj];
    }
    const float s2 = 1.0f / (sqrtf(ss2) + 1e-3f);
    float4* dst = (float4*)(outF + (by * 7 + bx) * 36);
#pragma unroll
    for (int q = 0; q < 9; ++q)
      dst[q] = make_float4(v[4 * q] * s2, v[4 * q + 1] * s2,
                           v[4 * q + 2] * s2, v[4 * q + 3] * s2);
  }
  // zero the pad region [3780, 4096)
  for (int i = 3780 + t; i < 4096; i += 256) outF[i] = 0.0f;
  // passthrough outputs
  if (t == 128) out[(size_t)B * 4096 + b] = (float)targets[b];
  if (t == 129) out[(size_t)B * 4096 + B + b] = (float)camid[b];
}

extern "C" void kernel_launch(void* const* d_in, const int* in_sizes, int n_in,
                              void* d_out, int out_size, void* d_ws, size_t ws_size,
                              hipStream_t stream) {
  const float* images = (const float*)d_in[0];
  const int* targets = (const int*)d_in[1];
  const int* camid = (const int*)d_in[2];
  float* out = (float*)d_out;
  const int B = in_sizes[1];  // 512
  hipLaunchKernelGGL(hog_kernel, dim3(B), dim3(256), 0, stream,
                     images, targets, camid, out, B);
}